// Round 1
// 433.568 us; speedup vs baseline: 1.1756x; 1.1756x over previous
//
#include <hip/hip_runtime.h>
#include <cstdint>
#include <cstddef>

typedef unsigned short u16;
typedef __attribute__((ext_vector_type(8))) short short8;   // 8 bf16 (4 VGPR)
typedef __attribute__((ext_vector_type(4))) float f32x4;    // MFMA C/D frag
typedef __attribute__((ext_vector_type(4))) int i32x4;

constexpr int M  = 8192;
constexpr int Nn = 4096;
constexpr int K1 = 2048;
constexpr int K2 = 4096;
constexpr int K  = K1 + K2;            // 6144
constexpr int BM = 256, BN = 256;
constexpr int NKT = K / 64;            // 96 K-tiles of BK=64
constexpr float LEAK = 0.3f;

__device__ __forceinline__ u16 f2bf(float f) {
  unsigned u = __float_as_uint(f);
  u += 0x7FFFu + ((u >> 16) & 1u);     // RNE
  return (u16)(u >> 16);
}

template<int C1, int C2>
__global__ void cast_concat(const float* __restrict__ X, const float* __restrict__ S,
                            u16* __restrict__ out, int rows)
{
  constexpr int C = C1 + C2;
  const size_t total = (size_t)rows * C / 8;
  for (size_t i = blockIdx.x * (size_t)blockDim.x + threadIdx.x; i < total;
       i += (size_t)gridDim.x * blockDim.x) {
    const size_t e = i * 8;
    const int r = (int)(e / C);
    const int c = (int)(e - (size_t)r * C);
    const float* src = (c < C1) ? (X + (size_t)r * C1 + c)
                                : (S + (size_t)r * C2 + (c - C1));
    const float4* s4 = (const float4*)src;
    float4 f0 = s4[0], f1 = s4[1];
    alignas(16) u16 tmp[8];
    tmp[0] = f2bf(f0.x); tmp[1] = f2bf(f0.y); tmp[2] = f2bf(f0.z); tmp[3] = f2bf(f0.w);
    tmp[4] = f2bf(f1.x); tmp[5] = f2bf(f1.y); tmp[6] = f2bf(f1.z); tmp[7] = f2bf(f1.w);
    *(i32x4*)(out + e) = *(i32x4*)tmp;
  }
}

__device__ __forceinline__ void gload16(const u16* g, u16* l) {
  // direct global->LDS DMA, 16B/lane; LDS dest = wave-uniform base + lane*16
  __builtin_amdgcn_global_load_lds(
      (const __attribute__((address_space(1))) void*)g,
      (__attribute__((address_space(3))) void*)l, 16, 0, 0);
}

__device__ __forceinline__ float fast_tanh(float x) {
  const float ax = __builtin_fabsf(x);
  const float e  = __builtin_amdgcn_exp2f(ax * 2.8853900817779268f); // 2*log2(e)
  const float r  = 1.0f - 2.0f * __builtin_amdgcn_rcpf(e + 1.0f);   // ax->inf: e=inf, r=1
  return __builtin_copysignf(r, x);
}

#define BAR()   __builtin_amdgcn_s_barrier()
#define LGKM0() asm volatile("s_waitcnt lgkmcnt(0)" ::: "memory")
#define VMW4()  asm volatile("s_waitcnt vmcnt(4)" ::: "memory")
#define VMW0()  asm volatile("s_waitcnt vmcnt(0)" ::: "memory")
#define SB0()   __builtin_amdgcn_sched_barrier(0)

// 256x256 tile, BK=64, 8-phase schedule (m201 template): per phase
// {ds_read subtile || 1 half-tile global_load_lds} -> barrier -> lgkmcnt(0)
// -> setprio(1) 16 MFMA setprio(0) -> [vmcnt(4) at ph4/ph8] -> barrier.
// LDS 128 KiB: A[2][2x128x64] + B[2][2x128x64] bf16. Swizzle: slot ^= row&7
// (8x16B slots/row), applied as inverse-swizzled GLOBAL source (linear LDS
// dest, required by global_load_lds) + swizzled ds_read address.
// Staging map (iter i, tiles T=2i in buf0 / T+1 in buf1):
//   p1,p2: A(T+1)->buf1   p3,p4: B(T+2)->buf0   p5,p6: A(T+2)->buf0
//   p7,p8: B(T+3)->buf1
// Every stage issues >=1 full barrier after its region's last read:
//   B(buf) dead after p2/p6; A(buf) dead after p3/p7. vmcnt(4) at p4 ensures
//   buf1 tile T+1 fully landed before p5; at p8 ensures buf0 tile T+2 landed
//   before next p1 (each wave waits its own loads, then barrier -> all).
__global__ __launch_bounds__(512, 2) void gemm_fused(
    const u16* __restrict__ A,      // [M][K] bf16
    const u16* __restrict__ W,      // [N][K] bf16
    const float* __restrict__ prev, // [M][N] fp32
    float* __restrict__ out)        // [M][N] fp32
{
  __shared__ u16 lds[65536];        // 128 KiB: A0|A1 @0,16384  B0|B1 @32768,49152

  const int tid  = threadIdx.x;
  const int lane = tid & 63;
  const int wid  = tid >> 6;
  const int wr   = wid >> 2;        // 0..1 -> 128-row half of C
  const int wc   = wid & 3;         // 0..3 -> 64-col quarter of C

  // XCD-aware bijective swizzle (512 % 8 == 0)
  const int cpx = gridDim.x >> 3;
  const int wg  = ((int)blockIdx.x & 7) * cpx + ((int)blockIdx.x >> 3);
  const int bn  = wg & 15;          // Nn/BN = 16
  const int bm  = wg >> 4;          // M/BM  = 32

  // ---- staging: per half-tile (128 rows x 64 cols) 2 gload16/thread.
  // dest byte o = c2*8192 + tid*16 -> row r=c2*64+(tid>>3), slot tid&7;
  // source col slot = (tid&7) ^ (r&7)  (inverse of read-side swizzle)
  const int sr = tid >> 3;
  const int ss = (tid & 7) ^ (sr & 7);
  const u16* pA = A + (size_t)(bm * BM + sr) * K + ss * 8;
  const u16* pW = W + (size_t)(bn * BN + sr) * K + ss * 8;
  u16* ldsw = lds + wid * 512;      // wave-uniform slot base
  const size_t rowK64  = (size_t)64  * K;
  const size_t rowK128 = (size_t)128 * K;

  auto stg = [&](const u16* g, int dst) {
    gload16(g,          ldsw + dst);
    gload16(g + rowK64, ldsw + dst + 4096);
  };

  // ---- fragment reads: logical slot c at row r lives at phys slot c^(r&7).
  // r&7 == lane&7 for all frags (row offsets are multiples of 16).
  const int fr  = lane & 15;
  const int khi = lane >> 4;
  const int lx  = lane & 7;
  const int aoff0 = wr * 8192 + fr * 64 + ((khi    ) ^ lx) * 8;   // ks=0
  const int aoff1 = wr * 8192 + fr * 64 + ((4 + khi) ^ lx) * 8;   // ks=1
  const int brow  = (wc & 1) * 64 + fr;
  const int boff0 = (wc >> 1) * 8192 + brow * 64 + ((khi    ) ^ lx) * 8;
  const int boff1 = (wc >> 1) * 8192 + brow * 64 + ((4 + khi) ^ lx) * 8;

  short8 af[4][2], bf[4][2];
  f32x4  acc[8][4];
  #pragma unroll
  for (int m = 0; m < 8; ++m)
    #pragma unroll
    for (int n = 0; n < 4; ++n) acc[m][n] = (f32x4)0.f;

  auto dsA = [&](int mg, int ab) {      // A m-group mg (4 rows-of-16), buf base ab
    #pragma unroll
    for (int mi = 0; mi < 4; ++mi) {
      af[mi][0] = *(const short8*)(lds + ab + aoff0 + (mg * 4 + mi) * 1024);
      af[mi][1] = *(const short8*)(lds + ab + aoff1 + (mg * 4 + mi) * 1024);
    }
  };
  auto dsB = [&](int ng, int bb) {      // B n-pair ng, buf base bb
    #pragma unroll
    for (int ni = 0; ni < 2; ++ni) {
      const int n = ng * 2 + ni;
      bf[n][0] = *(const short8*)(lds + bb + boff0 + n * 1024);
      bf[n][1] = *(const short8*)(lds + bb + boff1 + n * 1024);
    }
  };
  auto MM = [&](int mg, int ng) {       // one C-quadrant x K=64: 16 MFMA
    __builtin_amdgcn_s_setprio(1);
    #pragma unroll
    for (int ni = 0; ni < 2; ++ni)
      #pragma unroll
      for (int mi = 0; mi < 4; ++mi)
        #pragma unroll
        for (int ks = 0; ks < 2; ++ks)
          acc[mg * 4 + mi][ng * 2 + ni] = __builtin_amdgcn_mfma_f32_16x16x32_bf16(
              af[mi][ks], bf[ng * 2 + ni][ks], acc[mg * 4 + mi][ng * 2 + ni], 0, 0, 0);
    __builtin_amdgcn_s_setprio(0);
  };

  // ---- prologue: tile0 (B,A) -> buf0; tile1 B -> buf1; allow B(1) in flight
  stg(pW,                32768);
  stg(pW + rowK128,      32768 + 8192);
  stg(pA,                0);
  stg(pA + rowK128,      8192);
  stg(pW + 64,           49152);
  stg(pW + 64 + rowK128, 49152 + 8192);
  VMW4();
  BAR();

  const u16* gA = pA;
  const u16* gW = pW;
  #pragma unroll 1
  for (int i = 0; i < NKT / 2 - 1; ++i) {          // 47 iterations, T = 2i
    // ph1: quadrant (m0-3, n0-1) of tile T; stage A(T+1) h0 -> buf1
    dsA(0, 0); dsB(0, 32768);
    stg(gA + 64, 16384);
    BAR(); LGKM0(); SB0(); MM(0, 0); BAR();
    // ph2
    dsB(1, 32768);
    stg(gA + 64 + rowK128, 16384 + 8192);
    BAR(); LGKM0(); SB0(); MM(0, 1); BAR();
    // ph3
    dsA(1, 0);
    stg(gW + 128, 32768);
    BAR(); LGKM0(); SB0(); MM(1, 0); BAR();
    // ph4 (no ds reads)
    stg(gW + 128 + rowK128, 32768 + 8192);
    BAR(); MM(1, 1); VMW4(); BAR();
    // ph5: tile T+1 from buf1; stage A(T+2) h0 -> buf0
    dsA(0, 16384); dsB(0, 49152);
    stg(gA + 128, 0);
    BAR(); LGKM0(); SB0(); MM(0, 0); BAR();
    // ph6
    dsB(1, 49152);
    stg(gA + 128 + rowK128, 8192);
    BAR(); LGKM0(); SB0(); MM(0, 1); BAR();
    // ph7
    dsA(1, 16384);
    stg(gW + 192, 49152);
    BAR(); LGKM0(); SB0(); MM(1, 0); BAR();
    // ph8
    stg(gW + 192 + rowK128, 49152 + 8192);
    BAR(); MM(1, 1); VMW4(); BAR();
    gA += 128; gW += 128;
  }

  // ---- tail: tiles 94 (buf0), 95 (buf1); only A(95) left to stage
  dsA(0, 0); dsB(0, 32768);
  stg(gA + 64, 16384);
  BAR(); LGKM0(); SB0(); MM(0, 0); BAR();
  dsB(1, 32768);
  stg(gA + 64 + rowK128, 16384 + 8192);
  BAR(); LGKM0(); SB0(); MM(0, 1); BAR();
  dsA(1, 0);
  BAR(); LGKM0(); SB0(); MM(1, 0); BAR();
  BAR(); MM(1, 1); VMW0(); BAR();
  dsA(0, 16384); dsB(0, 49152);
  BAR(); LGKM0(); SB0(); MM(0, 0); BAR();
  dsB(1, 49152);
  BAR(); LGKM0(); SB0(); MM(0, 1); BAR();
  dsA(1, 16384);
  BAR(); LGKM0(); SB0(); MM(1, 0); BAR();
  BAR(); MM(1, 1);

  // ---- epilogue: C/D layout col=lane&15, row=(lane>>4)*4+j (unchanged)
  const int crow0 = bm * BM + wr * 128 + khi * 4;
  const int ccol0 = bn * BN + wc * 64 + fr;
  #pragma unroll
  for (int m = 0; m < 8; ++m)
    #pragma unroll
    for (int n = 0; n < 4; ++n)
      #pragma unroll
      for (int j = 0; j < 4; ++j) {
        const int row = crow0 + m * 16 + j;
        const size_t off = (size_t)row * Nn + ccol0 + n * 16;
        out[off] = (1.0f - LEAK) * prev[off] + LEAK * fast_tanh(acc[m][n][j]);
      }
}

extern "C" void kernel_launch(void* const* d_in, const int* in_sizes, int n_in,
                              void* d_out, int out_size, void* d_ws, size_t ws_size,
                              hipStream_t stream) {
  const float* inputs = (const float*)d_in[0];  // [8192][2048]
  const float* prev   = (const float*)d_in[1];  // [8192][4096]
  const float* w_in   = (const float*)d_in[2];  // [4096][2048]
  const float* w_res  = (const float*)d_in[3];  // [4096][4096]
  float* out = (float*)d_out;                   // [8192][4096]

  u16* Acat = (u16*)d_ws;                        // [M][K] bf16
  u16* Wcat = Acat + (size_t)M * K;              // [N][K] bf16

  cast_concat<K1, K2><<<2048, 256, 0, stream>>>(inputs, prev, Acat, M);
  cast_concat<K1, K2><<<1024, 256, 0, stream>>>(w_in, w_res, Wcat, Nn);

  gemm_fused<<<(M / BM) * (Nn / BN), 512, 0, stream>>>(Acat, Wcat, prev, out);
}

// Round 2
// 431.346 us; speedup vs baseline: 1.1816x; 1.0052x over previous
//
#include <hip/hip_runtime.h>
#include <cstdint>
#include <cstddef>

typedef unsigned short u16;
typedef __attribute__((ext_vector_type(8))) short short8;   // 8 bf16 (4 VGPR)
typedef __attribute__((ext_vector_type(4))) float f32x4;    // MFMA C/D frag
typedef __attribute__((ext_vector_type(4))) int i32x4;

constexpr int M  = 8192;
constexpr int Nn = 4096;
constexpr int K1 = 2048;
constexpr int K2 = 4096;
constexpr int K  = K1 + K2;            // 6144
constexpr int BM = 256, BN = 256;
constexpr int NKT = K / 64;            // 96 K-tiles of BK=64
constexpr float LEAK = 0.3f;

__device__ __forceinline__ u16 f2bf(float f) {
  unsigned u = __float_as_uint(f);
  u += 0x7FFFu + ((u >> 16) & 1u);     // RNE
  return (u16)(u >> 16);
}

template<int C1, int C2>
__global__ void cast_concat(const float* __restrict__ X, const float* __restrict__ S,
                            u16* __restrict__ out, int rows)
{
  constexpr int C = C1 + C2;
  const size_t total = (size_t)rows * C / 8;
  for (size_t i = blockIdx.x * (size_t)blockDim.x + threadIdx.x; i < total;
       i += (size_t)gridDim.x * blockDim.x) {
    const size_t e = i * 8;
    const int r = (int)(e / C);
    const int c = (int)(e - (size_t)r * C);
    const float* src = (c < C1) ? (X + (size_t)r * C1 + c)
                                : (S + (size_t)r * C2 + (c - C1));
    const float4* s4 = (const float4*)src;
    float4 f0 = s4[0], f1 = s4[1];
    alignas(16) u16 tmp[8];
    tmp[0] = f2bf(f0.x); tmp[1] = f2bf(f0.y); tmp[2] = f2bf(f0.z); tmp[3] = f2bf(f0.w);
    tmp[4] = f2bf(f1.x); tmp[5] = f2bf(f1.y); tmp[6] = f2bf(f1.z); tmp[7] = f2bf(f1.w);
    *(i32x4*)(out + e) = *(i32x4*)tmp;
  }
}

__device__ __forceinline__ void gload16(const u16* g, u16* l) {
  __builtin_amdgcn_global_load_lds(
      (const __attribute__((address_space(1))) void*)g,
      (__attribute__((address_space(3))) void*)l, 16, 0, 0);
}

__device__ __forceinline__ float fast_tanh(float x) {
  const float ax = __builtin_fabsf(x);
  const float e  = __builtin_amdgcn_exp2f(ax * 2.8853900817779268f); // 2*log2(e)
  const float r  = 1.0f - 2.0f * __builtin_amdgcn_rcpf(e + 1.0f);
  return __builtin_copysignf(r, x);
}

#define BAR()   __builtin_amdgcn_s_barrier()
#define LGKM0() asm volatile("s_waitcnt lgkmcnt(0)" ::: "memory")
#define LGKM4() asm volatile("s_waitcnt lgkmcnt(4)" ::: "memory")
#define LGKM8() asm volatile("s_waitcnt lgkmcnt(8)" ::: "memory")
#define VMW2()  asm volatile("s_waitcnt vmcnt(2)" ::: "memory")
#define VMW4()  asm volatile("s_waitcnt vmcnt(4)" ::: "memory")
#define VMW0()  asm volatile("s_waitcnt vmcnt(0)" ::: "memory")
#define SB0()   __builtin_amdgcn_sched_barrier(0)

// 256x256 tile, BK=64, 8-phase pipelined schedule with ONE barrier/phase and
// frag reads ONE PHASE AHEAD into double-buffered register sets (afE/afO,
// bfE/bfO). Phase p: {issue reads for p+1} {issue 1 half-tile stg}
// {lgkmcnt(n_issued) -> retires p's operand reads (DS in-order)} {16 MFMA}
// {vmcnt(2) where scheduled} {barrier}. LDS reads drain UNDER the MFMA
// cluster -> read/MFMA overlap (round-1's 2-barrier phases serialized them).
// Buffers: A0@0 A1@16384 B0@32768 B1@49152 (u16 els), h1 = +8192.
// Read-issue map (iter tiles T=2i buf0, T+1 buf1):
//  ph1:bfO(ng1,T,B0)  ph2:afO(mg1,T,A0)  ph3:afE(mg0,T+1,A1) ph4:bfE(ng0,T+1,B1)
//  ph5:bfO(ng1,T+1)   ph6:afO(mg1,T+1)   ph7:afE(mg0,T+2,A0) ph8:bfE(ng0,T+2,B0)
// Staging map (1 stg = 2 gload16 per phase):
//  ph1:A(T+1)h1 ph2:B(T+1)h1 ph3:B(T+2)h0 ph4:A(T+2)h0
//  ph5:A(T+2)h1 ph6:B(T+2)h1 ph7:B(T+3)h0 ph8:A(T+3)h0
// vmcnt(2) at ends of ph2 (A(T+1) landed before ph3 reads), ph3 (B(T+1)
// before ph4), ph6 (A(T+2) before ph7), ph7 (B(T+2) before ph8). Write-after-
// read: every stg targets a region whose last reads were lgkm-retired at the
// previous phase's counted wait, then separated by that phase's barrier.
// Read-hoist past raw s_barrier is blocked by the "memory"-clobbered vmcnt
// asm at exactly the landing points; elsewhere early reads are data-safe.
__global__ __launch_bounds__(512, 2) void gemm_fused(
    const u16* __restrict__ A,      // [M][K] bf16
    const u16* __restrict__ W,      // [N][K] bf16
    const float* __restrict__ prev, // [M][N] fp32
    float* __restrict__ out)        // [M][N] fp32
{
  __shared__ u16 lds[65536];        // 128 KiB

  const int tid  = threadIdx.x;
  const int lane = tid & 63;
  const int wid  = tid >> 6;
  const int wr   = wid >> 2;        // 0..1 -> 128-row half of C
  const int wc   = wid & 3;         // 0..3 -> 64-col quarter of C

  // XCD-aware bijective swizzle (512 % 8 == 0)
  const int cpx = gridDim.x >> 3;
  const int wg  = ((int)blockIdx.x & 7) * cpx + ((int)blockIdx.x >> 3);
  const int bn  = wg & 15;          // Nn/BN = 16
  const int bm  = wg >> 4;          // M/BM  = 32

  // staging: one gload16 = 64 rows x 64 cols; stg = rows r, r+64 (128 rows)
  const int sr = tid >> 3;          // 0..63
  const int ss = (tid & 7) ^ (sr & 7);   // inverse swizzle on global source
  const u16* pA = A + (size_t)(bm * BM + sr) * K + ss * 8;
  const u16* pW = W + (size_t)(bn * BN + sr) * K + ss * 8;
  u16* ldsw = lds + wid * 512;
  const size_t rowK64  = (size_t)64  * K;
  const size_t rowK128 = (size_t)128 * K;

  auto stg = [&](const u16* g, int dst) {
    gload16(g,          ldsw + dst);
    gload16(g + rowK64, ldsw + dst + 4096);
  };

  // fragment read addressing (phys slot c^(r&7), r&7 == lane&7 for all frags)
  const int fr  = lane & 15;
  const int khi = lane >> 4;
  const int lx  = lane & 7;
  const int aoff0 = wr * 8192 + fr * 64 + ((khi    ) ^ lx) * 8;   // ks=0
  const int aoff1 = wr * 8192 + fr * 64 + ((4 + khi) ^ lx) * 8;   // ks=1
  const int brow  = (wc & 1) * 64 + fr;
  const int boff0 = (wc >> 1) * 8192 + brow * 64 + ((khi    ) ^ lx) * 8;
  const int boff1 = (wc >> 1) * 8192 + brow * 64 + ((4 + khi) ^ lx) * 8;

  short8 afE[4][2], afO[4][2];      // A frag sets (mg alternates)
  short8 bfE[2][2], bfO[2][2];      // B frag sets (ng alternates)
  f32x4  acc[8][4];
  #pragma unroll
  for (int m = 0; m < 8; ++m)
    #pragma unroll
    for (int n = 0; n < 4; ++n) acc[m][n] = (f32x4)0.f;

  auto dsA = [&](short8 (&Av)[4][2], int mg, int ab) {
    #pragma unroll
    for (int mi = 0; mi < 4; ++mi) {
      Av[mi][0] = *(const short8*)(lds + ab + aoff0 + (mg * 4 + mi) * 1024);
      Av[mi][1] = *(const short8*)(lds + ab + aoff1 + (mg * 4 + mi) * 1024);
    }
  };
  auto dsB = [&](short8 (&Bv)[2][2], int ng, int bb) {
    #pragma unroll
    for (int ni = 0; ni < 2; ++ni) {
      Bv[ni][0] = *(const short8*)(lds + bb + boff0 + (ng * 2 + ni) * 1024);
      Bv[ni][1] = *(const short8*)(lds + bb + boff1 + (ng * 2 + ni) * 1024);
    }
  };
  auto MM = [&](short8 (&Av)[4][2], short8 (&Bv)[2][2], int mg, int ng) {
    __builtin_amdgcn_s_setprio(1);
    #pragma unroll
    for (int ni = 0; ni < 2; ++ni)
      #pragma unroll
      for (int mi = 0; mi < 4; ++mi)
        #pragma unroll
        for (int ks = 0; ks < 2; ++ks)
          acc[mg * 4 + mi][ng * 2 + ni] = __builtin_amdgcn_mfma_f32_16x16x32_bf16(
              Av[mi][ks], Bv[ni][ks], acc[mg * 4 + mi][ng * 2 + ni], 0, 0, 0);
    __builtin_amdgcn_s_setprio(0);
  };

  // ---- prologue: A(0),B(0) full; B(1)h0; A(1)h0 (12 loads, keep last 4 in flight)
  stg(pA,            0);
  stg(pA + rowK128,  8192);
  stg(pW,            32768);
  stg(pW + rowK128,  32768 + 8192);
  stg(pW + 64,       49152);
  stg(pA + 64,       16384);
  VMW4();
  BAR();
  dsA(afE, 0, 0);                    // mg0, tile0, A0
  dsB(bfE, 0, 32768);                // ng0, tile0, B0

  const u16* gA = pA;
  const u16* gW = pW;
  #pragma unroll 1
  for (int i = 0; i < 47; ++i) {     // tiles T=2i (buf0), T+1 (buf1); stages T+2,T+3
    // ph1
    dsB(bfO, 1, 32768);
    stg(gA + 64 + rowK128, 16384 + 8192);   // A(T+1)h1
    LGKM4(); SB0(); MM(afE, bfE, 0, 0); BAR();
    // ph2
    dsA(afO, 1, 0);
    stg(gW + 64 + rowK128, 49152 + 8192);   // B(T+1)h1
    LGKM8(); SB0(); MM(afE, bfO, 0, 1); VMW2(); BAR();
    // ph3
    dsA(afE, 0, 16384);
    stg(gW + 128, 32768);                   // B(T+2)h0
    LGKM8(); SB0(); MM(afO, bfE, 1, 0); VMW2(); BAR();
    // ph4 (operands retired by ph3's wait)
    dsB(bfE, 0, 49152);
    stg(gA + 128, 0);                       // A(T+2)h0
    SB0(); MM(afO, bfO, 1, 1); BAR();
    // ph5
    dsB(bfO, 1, 49152);
    stg(gA + 128 + rowK128, 8192);          // A(T+2)h1
    LGKM4(); SB0(); MM(afE, bfE, 0, 0); BAR();
    // ph6
    dsA(afO, 1, 16384);
    stg(gW + 128 + rowK128, 32768 + 8192);  // B(T+2)h1
    LGKM8(); SB0(); MM(afE, bfO, 0, 1); VMW2(); BAR();
    // ph7
    dsA(afE, 0, 0);
    stg(gW + 192, 49152);                   // B(T+3)h0
    LGKM8(); SB0(); MM(afO, bfE, 1, 0); VMW2(); BAR();
    // ph8
    dsB(bfE, 0, 32768);
    stg(gA + 192, 16384);                   // A(T+3)h0
    SB0(); MM(afO, bfO, 1, 1); BAR();
    gA += 128; gW += 128;
  }

  // ---- tail: tiles 94 (buf0), 95 (buf1); stage only A(95)h1, B(95)h1
  // tp1
  dsB(bfO, 1, 32768);
  stg(gA + 64 + rowK128, 16384 + 8192);     // A(95)h1
  LGKM4(); SB0(); MM(afE, bfE, 0, 0); BAR();
  // tp2
  dsA(afO, 1, 0);
  stg(gW + 64 + rowK128, 49152 + 8192);     // B(95)h1
  LGKM8(); SB0(); MM(afE, bfO, 0, 1); VMW2(); BAR();
  // tp3
  dsA(afE, 0, 16384);
  LGKM8(); SB0(); MM(afO, bfE, 1, 0); VMW0(); BAR();
  // tp4
  dsB(bfE, 0, 49152);
  SB0(); MM(afO, bfO, 1, 1); BAR();
  // tp5
  dsB(bfO, 1, 49152);
  LGKM4(); SB0(); MM(afE, bfE, 0, 0); BAR();
  // tp6
  dsA(afO, 1, 16384);
  LGKM8(); SB0(); MM(afE, bfO, 0, 1); BAR();
  // tp7
  LGKM0(); SB0(); MM(afO, bfE, 1, 0);
  // tp8
  MM(afO, bfO, 1, 1);

  // ---- epilogue: C/D layout col=lane&15, row=(lane>>4)*4+j
  const int crow0 = bm * BM + wr * 128 + khi * 4;
  const int ccol0 = bn * BN + wc * 64 + fr;
  #pragma unroll
  for (int m = 0; m < 8; ++m)
    #pragma unroll
    for (int n = 0; n < 4; ++n)
      #pragma unroll
      for (int j = 0; j < 4; ++j) {
        const int row = crow0 + m * 16 + j;
        const size_t off = (size_t)row * Nn + ccol0 + n * 16;
        out[off] = (1.0f - LEAK) * prev[off] + LEAK * fast_tanh(acc[m][n][j]);
      }
}

extern "C" void kernel_launch(void* const* d_in, const int* in_sizes, int n_in,
                              void* d_out, int out_size, void* d_ws, size_t ws_size,
                              hipStream_t stream) {
  const float* inputs = (const float*)d_in[0];  // [8192][2048]
  const float* prev   = (const float*)d_in[1];  // [8192][4096]
  const float* w_in   = (const float*)d_in[2];  // [4096][2048]
  const float* w_res  = (const float*)d_in[3];  // [4096][4096]
  float* out = (float*)d_out;                   // [8192][4096]

  u16* Acat = (u16*)d_ws;                        // [M][K] bf16
  u16* Wcat = Acat + (size_t)M * K;              // [N][K] bf16

  cast_concat<K1, K2><<<2048, 256, 0, stream>>>(inputs, prev, Acat, M);
  cast_concat<K1, K2><<<1024, 256, 0, stream>>>(w_in, w_res, Wcat, Nn);

  gemm_fused<<<(M / BM) * (Nn / BN), 512, 0, stream>>>(Acat, Wcat, prev, out);
}